// Round 4
// baseline (281.367 us; speedup 1.0000x reference)
//
#include <hip/hip_runtime.h>
#include <hip/hip_bf16.h>

#define BATCH 4096
#define NTHR 512

typedef __attribute__((ext_vector_type(8))) short bf16x8;
typedef __attribute__((ext_vector_type(4))) float f32x4;
typedef __attribute__((ext_vector_type(4))) short short4v;

// CK-style barrier: drain LDS only, leave global loads in flight
#define BAR() asm volatile("s_waitcnt lgkmcnt(0)\n\ts_barrier" ::: "memory")

// dh-sorted packing: group g (= degree) has cnt(g) units, prefix off1(g)
__host__ __device__ __forceinline__ int off1(int g) { return (g <= 16) ? 17 * g : 16 * g + 16; }
__host__ __device__ __forceinline__ int cntg(int g) { return (g < 16) ? 17 : 16; }
__host__ __device__ __forceinline__ int unitOf(int p) {
    int gp, jp;
    if (p < 272) { gp = p / 17; jp = p - gp * 17; }
    else         { gp = (p >> 4) - 1; jp = p & 15; }
    return gp + 63 * jp;
}
__device__ __forceinline__ short f2bf(float f) {
    __hip_bfloat16 h = __float2bfloat16(f);
    return *reinterpret_cast<short*>(&h);
}

// ---------------- prep4 ----------------
// W1f [g][tile(64)][lane][8] : B[k=(lane>>4)*8+e][n=lane&15] = W1[unit(tile*16+n)][g+63k], k<cnt(g)
// W2f [g][c(8)][lane][8]     : B[k][n] = W2[c*16+n][g+63k], k<cnt(g)
// W0f [g][n2(2)][kt(2)][lane][8] : slot p=off1(g)+n2*16+n; k'=kt*32+(lane>>4)*8+e;
//     k'==0 -> b0[unit(p)]; else (k'-1<=g) -> W0[unit(p)][k'-1]; else 0
// b1p [1024] f32 packed b1
__global__ void prep4(const float* __restrict__ W0, const float* __restrict__ b0,
                      const float* __restrict__ W1, const float* __restrict__ b1,
                      const float* __restrict__ W2,
                      short* __restrict__ W1f, short* __restrict__ W2f,
                      short* __restrict__ W0f, float* __restrict__ b1p) {
    __shared__ short ws[16][1024];
    const int b = blockIdx.x, t = threadIdx.x;
    if (b < 72) {
        const bool isW1 = (b < 64);
        const int n = t >> 4;
        const int u = isW1 ? unitOf(b * 16 + n) : ((b - 64) * 16 + n);
        const float* src = isW1 ? (W1 + (long)u * 1024) : (W2 + (long)u * 1024);
        const int c0 = (t & 15) * 4;
#pragma unroll
        for (int j = 0; j < 16; ++j) {
            int c = c0 + j * 64;
            float4 v = *(const float4*)&src[c];
            short4v sv;
            sv[0] = f2bf(v.x); sv[1] = f2bf(v.y); sv[2] = f2bf(v.z); sv[3] = f2bf(v.w);
            *(short4v*)&ws[n][c] = sv;
        }
        __syncthreads();
#pragma unroll 1
        for (int it = 0; it < 16; ++it) {
            int v = t + it * 256;
            if (v < 4032) {
                int g = v >> 6, lane2 = v & 63;
                int nn = lane2 & 15, aq2 = lane2 >> 4;
                bf16x8 pk;
#pragma unroll
                for (int e = 0; e < 8; ++e) {
                    int k = aq2 * 8 + e;
                    pk[e] = (k < cntg(g)) ? ws[nn][g + 63 * k] : (short)0;
                }
                if (isW1) *(bf16x8*)&W1f[(((long)g * 64 + b) * 64 + lane2) * 8] = pk;
                else      *(bf16x8*)&W2f[(((long)g * 8 + (b - 64)) * 64 + lane2) * 8] = pk;
            }
        }
    } else if (b < 88) {
        const int bb = b - 72;
#pragma unroll 1
        for (int j = 0; j < 32; ++j) {
            int q = t + j * 256;
            if (q < 8064) {
                int idx = bb * 8064 + q;
                int g = idx >> 11, rem = idx & 2047;
                int n2 = rem >> 10, kt = (rem >> 9) & 1, lane2 = (rem >> 3) & 63, e = rem & 7;
                int sl = n2 * 16 + (lane2 & 15);
                int kp = kt * 32 + ((lane2 >> 4) << 3) + e;
                float val = 0.f;
                if (sl < cntg(g)) {
                    int u = unitOf(off1(g) + sl);
                    if (kp == 0) val = b0[u];
                    else if (kp - 1 <= g) val = W0[u * 64 + kp - 1];
                }
                W0f[idx] = f2bf(val);
            }
        }
    } else {
        for (int p = t; p < 1024; p += 256) b1p[p] = b1[unitOf(p)];
    }
}

// ---------------- made4: 2-window wave-specialized step ----------------
__global__ __launch_bounds__(NTHR, 2) void made4(
    const float* __restrict__ uin, const float* __restrict__ b2,
    const short* __restrict__ W1f, const short* __restrict__ W2f,
    const short* __restrict__ W0f, const float* __restrict__ b1p,
    float* __restrict__ out) {

    __shared__ __align__(16) short h1g[16][32];   // group-g h1, A-frag [m][j], K-pad zeroed
    __shared__ __align__(16) short h2g[16][32];   // group-g h2
    __shared__ __align__(16) short xhist[16][72]; // [m][k']: k'=0 -> 1.0 (bias), k'=i+1 -> x_i
    __shared__ __align__(16) float uT[64][16];    // u transposed: uT[i][m]
    __shared__ __align__(16) float xLs[16][68];   // staged x for final store

    const int t = threadIdx.x, lane = t & 63, wv = t >> 6;
    const int n = lane & 15, aq = lane >> 4;
    const int rowbase = blockIdx.x * 16;

    {   // zero h1g + xhist (K pads must stay 0)
        int* z1 = (int*)&h1g[0][0];
        for (int idx = t; idx < 16 * 32 / 2; idx += NTHR) z1[idx] = 0;
        int* z2 = (int*)&xhist[0][0];
        for (int idx = t; idx < 16 * 72 / 2; idx += NTHR) z2[idx] = 0;
    }
    if (t < 256) {   // transpose u into uT
        int r = t >> 4, c0 = (t & 15) * 4;
        float4 v = *(const float4*)&uin[(long)(rowbase + r) * 64 + c0];
        uT[c0 + 0][r] = v.x; uT[c0 + 1][r] = v.y; uT[c0 + 2][r] = v.z; uT[c0 + 3][r] = v.w;
    }
    BAR();
    if (t < 16) xhist[t][0] = (short)0x3F80;   // bf16 1.0 (bias column)

    // acc2: pre2 tiles, contiguous ownership (wave wv owns tiles 8wv..8wv+7); bias folded in
    f32x4 acc2[8];
#pragma unroll
    for (int s = 0; s < 8; ++s) {
        float bb = b1p[(wv * 8 + s) * 16 + n];
        acc2[s] = (f32x4){bb, bb, bb, bb};
    }
    // zacc: all 128 z cols on wave 0 (col r = c*16+n), bias b2 folded in
    f32x4 zacc[8];
    if (wv == 0) {
#pragma unroll
        for (int c = 0; c < 8; ++c) {
            float bz = b2[c * 16 + n];
            zacc[c] = (f32x4){bz, bz, bz, bz};
        }
    }

    // prefetch registers
    bf16x8 w1f[8], w2f[8], w0f00, w0f01, w0f10, w0f11;
#pragma unroll
    for (int s = 0; s < 8; ++s)
        w1f[s] = *(const bf16x8*)&W1f[(((long)0 * 64 + (wv * 8 + s)) * 64 + lane) * 8];
    if (wv == 0) {
#pragma unroll
        for (int c = 0; c < 8; ++c)
            w2f[c] = *(const bf16x8*)&W2f[(((long)0 * 8 + c) * 64 + lane) * 8];
        w0f00 = *(const bf16x8*)&W0f[((((long)0 * 2 + 0) * 2 + 0) * 64 + lane) * 8];
        w0f01 = *(const bf16x8*)&W0f[((((long)0 * 2 + 0) * 2 + 1) * 64 + lane) * 8];
        w0f10 = *(const bf16x8*)&W0f[((((long)0 * 2 + 1) * 2 + 0) * 64 + lane) * 8];
        w0f11 = *(const bf16x8*)&W0f[((((long)0 * 2 + 1) * 2 + 1) * 64 + lane) * 8];
    }
    f32x4 ldjacc = {0.f, 0.f, 0.f, 0.f};

#pragma unroll 1
    for (int i = 0; i < 64; ++i) {
        // ========== V1: bulk acc2 update (all waves) + h2 finalize-extract ==========
        if (i > 0) {
            const int g = i - 1;
            const int og = off1(g), cg = cntg(g);
            const int tf0 = og >> 4, tfl = (og + cg - 1) >> 4;
            const bf16x8 af = *(const bf16x8*)&h1g[n][aq * 8];
            const int s0 = tf0 - wv * 8;   // first active local tile (may be <0 / >7)
#pragma unroll
            for (int s = 0; s < 8; ++s) {
                if (s >= s0)
                    acc2[s] = __builtin_amdgcn_mfma_f32_16x16x32_bf16(af, w1f[s], acc2[s], 0, 0, 0);
            }
            {   // prefetch W1f group i (consumed next V1)
                const int gN = (i < 63) ? i : 62;
                const int s0n = (off1(gN) >> 4) - wv * 8;
#pragma unroll
                for (int s = 0; s < 8; ++s) {
                    if (s >= s0n)
                        w1f[s] = *(const bf16x8*)&W1f[(((long)gN * 64 + (wv * 8 + s)) * 64 + lane) * 8];
                }
            }
            // finalize: relu(acc2) of owning tile(s) -> h2g
#pragma unroll
            for (int s = 0; s < 8; ++s) {
                const int T = wv * 8 + s;
                if (T == tf0 || T == tfl) {
                    const int j = T * 16 + n - og;
                    if (j >= 0 && j < cg) {
#pragma unroll
                        for (int r = 0; r < 4; ++r) {
                            float v = acc2[s][r];
                            v = v > 0.f ? v : 0.f;
                            h2g[aq * 4 + r][j] = f2bf(v);
                        }
                    }
                }
            }
            if (cg == 16 && wv == (tf0 >> 3) && n == 0) {   // keep col 16 zero after 17-wide groups
#pragma unroll
                for (int r = 0; r < 4; ++r) h2g[aq * 4 + r][16] = 0;
            }
        }
        BAR();

        // ========== V2: wave 0 only — z update, publish, x, h1 group i ==========
        if (wv == 0) {
            if (i > 0) {
                const bf16x8 af2 = *(const bf16x8*)&h2g[n][aq * 8];
#pragma unroll
                for (int c = 0; c < 8; ++c)
                    zacc[c] = __builtin_amdgcn_mfma_f32_16x16x32_bf16(af2, w2f[c], zacc[c], 0, 0, 0);
                const int gN = (i < 63) ? i : 62;   // prefetch W2f (consumed next V2)
#pragma unroll
                for (int c = 0; c < 8; ++c)
                    w2f[c] = *(const bf16x8*)&W2f[(((long)gN * 8 + c) * 64 + lane) * 8];
            }
            // publish mu_i (col i) and sigma_i (col 64+i): in-register
            const int c0 = i >> 4;
            f32x4 za, zb;
            switch (c0) {
                case 0:  za = zacc[0]; zb = zacc[4]; break;
                case 1:  za = zacc[1]; zb = zacc[5]; break;
                case 2:  za = zacc[2]; zb = zacc[6]; break;
                default: za = zacc[3]; zb = zacc[7]; break;
            }
            const int n0 = i & 15;
            float4 uv4 = *(const float4*)&uT[i][aq * 4];
            float ua[4] = {uv4.x, uv4.y, uv4.z, uv4.w};
            float xr[4];
#pragma unroll
            for (int r = 0; r < 4; ++r)
                xr[r] = ua[r] * __expf(zb[r]) + za[r];
            if (n == n0) {
#pragma unroll
                for (int r = 0; r < 4; ++r) {
                    ldjacc[r] += zb[r];
                    xLs[aq * 4 + r][i] = xr[r];
                    if (i < 63) xhist[aq * 4 + r][i + 1] = f2bf(xr[r]);
                }
            }
            if (i < 63) {
                const int cg2 = cntg(i);
                const bool two_k = (i + 1 >= 32);
                const bf16x8 ax0 = *(const bf16x8*)&xhist[n][aq * 8];
                f32x4 d0 = {0.f, 0.f, 0.f, 0.f};
                d0 = __builtin_amdgcn_mfma_f32_16x16x32_bf16(ax0, w0f00, d0, 0, 0, 0);
                f32x4 d1 = {0.f, 0.f, 0.f, 0.f};
                if (two_k) {
                    const bf16x8 ax1 = *(const bf16x8*)&xhist[n][32 + aq * 8];
                    d0 = __builtin_amdgcn_mfma_f32_16x16x32_bf16(ax1, w0f01, d0, 0, 0, 0);
                    if (cg2 == 17) {
                        d1 = __builtin_amdgcn_mfma_f32_16x16x32_bf16(ax0, w0f10, d1, 0, 0, 0);
                        d1 = __builtin_amdgcn_mfma_f32_16x16x32_bf16(ax1, w0f11, d1, 0, 0, 0);
                    }
                } else if (cg2 == 17) {
                    d1 = __builtin_amdgcn_mfma_f32_16x16x32_bf16(ax0, w0f10, d1, 0, 0, 0);
                }
                // write h1 group i: cols j=n (+ col 16 from d1 or zero)
#pragma unroll
                for (int r = 0; r < 4; ++r) {
                    float v = d0[r];
                    v = v > 0.f ? v : 0.f;
                    h1g[aq * 4 + r][n] = f2bf(v);
                }
                if (n == 0) {
#pragma unroll
                    for (int r = 0; r < 4; ++r) {
                        float v = (cg2 == 17) ? (d1[r] > 0.f ? d1[r] : 0.f) : 0.f;
                        h1g[aq * 4 + r][16] = f2bf(v);
                    }
                }
                // prefetch W0f group i+1 (consumed next V2)
                const int gN2 = (i + 1 < 63) ? (i + 1) : 62;
                w0f00 = *(const bf16x8*)&W0f[((((long)gN2 * 2 + 0) * 2 + 0) * 64 + lane) * 8];
                w0f01 = *(const bf16x8*)&W0f[((((long)gN2 * 2 + 0) * 2 + 1) * 64 + lane) * 8];
                w0f10 = *(const bf16x8*)&W0f[((((long)gN2 * 2 + 1) * 2 + 0) * 64 + lane) * 8];
                w0f11 = *(const bf16x8*)&W0f[((((long)gN2 * 2 + 1) * 2 + 1) * 64 + lane) * 8];
            }
        }
        BAR();
    }

    // outputs
    if (t < 256) {
        int r = t >> 4, c = (t & 15) * 4;
        float4 v;
        v.x = xLs[r][c]; v.y = xLs[r][c + 1]; v.z = xLs[r][c + 2]; v.w = xLs[r][c + 3];
        *(float4*)&out[(long)(rowbase + r) * 64 + c] = v;
    }
    if (wv == 0) {
#pragma unroll
        for (int r = 0; r < 4; ++r) {
            float x = ldjacc[r];
            x += __shfl_xor(x, 1);
            x += __shfl_xor(x, 2);
            x += __shfl_xor(x, 4);
            x += __shfl_xor(x, 8);
            if (n == 0) out[(long)BATCH * 64 + rowbase + aq * 4 + r] = x;
        }
    }
}

extern "C" void kernel_launch(void* const* d_in, const int* in_sizes, int n_in,
                              void* d_out, int out_size, void* d_ws, size_t ws_size,
                              hipStream_t stream) {
    (void)in_sizes; (void)n_in; (void)out_size; (void)ws_size;
    const float* u  = (const float*)d_in[0];
    const float* W0 = (const float*)d_in[1];
    const float* b0 = (const float*)d_in[2];
    const float* W1 = (const float*)d_in[3];
    const float* b1 = (const float*)d_in[4];
    const float* W2 = (const float*)d_in[5];
    const float* b2 = (const float*)d_in[6];
    float* out = (float*)d_out;

    // d_ws layout (bytes): W1f 4,128,768 | W2f 516,096 | W0f 258,048 | b1p 4,096
    short* W1f = (short*)d_ws;
    short* W2f = (short*)((char*)d_ws + 4128768);
    short* W0f = (short*)((char*)d_ws + 4128768 + 516096);
    float* b1p = (float*)((char*)d_ws + 4128768 + 516096 + 258048);

    prep4<<<dim3(89), dim3(256), 0, stream>>>(W0, b0, W1, b1, W2, W1f, W2f, W0f, b1p);
    made4<<<dim3(BATCH / 16), dim3(NTHR), 0, stream>>>(u, b2, W1f, W2f, W0f, b1p, out);
}

// Round 5
// 209.535 us; speedup vs baseline: 1.3428x; 1.3428x over previous
//
#include <hip/hip_runtime.h>
#include <hip/hip_bf16.h>

#define BATCH 4096
#define NTHR 512

typedef __attribute__((ext_vector_type(8))) short bf16x8;
typedef __attribute__((ext_vector_type(4))) float f32x4;
typedef __attribute__((ext_vector_type(4))) short short4v;

#define BAR() asm volatile("s_waitcnt lgkmcnt(0)\n\ts_barrier" ::: "memory")

__host__ __device__ __forceinline__ int off1(int g) { return (g <= 16) ? 17 * g : 16 * g + 16; }
__host__ __device__ __forceinline__ int cntg(int g) { return (g < 16) ? 17 : 16; }
__host__ __device__ __forceinline__ int unitOf(int p) {
    int gp, jp;
    if (p < 272) { gp = p / 17; jp = p - gp * 17; }
    else         { gp = (p >> 4) - 1; jp = p & 15; }
    return gp + 63 * jp;
}
__device__ __forceinline__ short f2bf(float f) {
    __hip_bfloat16 h = __float2bfloat16(f);
    return *reinterpret_cast<short*>(&h);
}

__global__ void prep5(const float* __restrict__ W0, const float* __restrict__ b0,
                      const float* __restrict__ W1, const float* __restrict__ b1,
                      const float* __restrict__ W2,
                      short* __restrict__ W1f, short* __restrict__ W2f,
                      short* __restrict__ W0f, float* __restrict__ b1p) {
    __shared__ short ws[16][1024];
    const int b = blockIdx.x, t = threadIdx.x;
    if (b < 72) {
        const bool isW1 = (b < 64);
        const int n = t >> 4;
        int u;
        if (isW1) u = unitOf(b * 16 + n);
        else {
            const int c = b - 64;
            u = (n & 1) ? (64 + c * 8 + (n >> 1)) : (c * 8 + (n >> 1));
        }
        const float* src = isW1 ? (W1 + (long)u * 1024) : (W2 + (long)u * 1024);
        const int c0 = (t & 15) * 4;
#pragma unroll
        for (int j = 0; j < 16; ++j) {
            int c = c0 + j * 64;
            float4 v = *(const float4*)&src[c];
            short4v sv;
            sv[0] = f2bf(v.x); sv[1] = f2bf(v.y); sv[2] = f2bf(v.z); sv[3] = f2bf(v.w);
            *(short4v*)&ws[n][c] = sv;
        }
        __syncthreads();
#pragma unroll 1
        for (int it = 0; it < 16; ++it) {
            int v = t + it * 256;
            if (v < 4032) {
                int g = v >> 6, lane2 = v & 63;
                int nn = lane2 & 15, aq2 = lane2 >> 4;
                bf16x8 pk;
#pragma unroll
                for (int e = 0; e < 8; ++e) {
                    int k = aq2 * 8 + e;
                    pk[e] = (k < cntg(g)) ? ws[nn][g + 63 * k] : (short)0;
                }
                if (isW1) *(bf16x8*)&W1f[(((long)g * 64 + b) * 64 + lane2) * 8] = pk;
                else      *(bf16x8*)&W2f[(((long)g * 8 + (b - 64)) * 64 + lane2) * 8] = pk;
            }
        }
    } else if (b < 88) {
        const int bb = b - 72;
#pragma unroll 1
        for (int j = 0; j < 32; ++j) {
            int q = t + j * 256;
            if (q < 8064) {
                int idx = bb * 8064 + q;
                int g = idx >> 11, rem = idx & 2047;
                int n2 = rem >> 10, kt = (rem >> 9) & 1, lane2 = (rem >> 3) & 63, e = rem & 7;
                int sl = n2 * 16 + (lane2 & 15);
                int kp = kt * 32 + ((lane2 >> 4) << 3) + e;
                float val = 0.f;
                if (sl < cntg(g)) {
                    int u = unitOf(off1(g) + sl);
                    if (kp == 0) val = b0[u];
                    else if (kp - 1 <= g) val = W0[u * 64 + kp - 1];
                }
                W0f[idx] = f2bf(val);
            }
        }
    } else {
        for (int p = t; p < 1024; p += 256) b1p[p] = b1[unitOf(p)];
    }
}

__global__ __launch_bounds__(NTHR, 2) void made5(
    const float* __restrict__ uin, const float* __restrict__ b2,
    const short* __restrict__ W1f, const short* __restrict__ W2f,
    const short* __restrict__ W0f, const float* __restrict__ b1p,
    float* __restrict__ out) {

    __shared__ __align__(16) short h1g[16][40];
    __shared__ __align__(16) short h2g[16][40];
    __shared__ __align__(16) short xhist[16][80];
    __shared__ __align__(16) float uT[64][16];
    __shared__ __align__(16) float xLs[16][68];
    __shared__ float ldjpart[8][16];

    const int t = threadIdx.x, lane = t & 63, wv = t >> 6;
    const int n = lane & 15, aq = lane >> 4;
    const int rowbase = blockIdx.x * 16;

    {
        int* z1 = (int*)&h1g[0][0];
        for (int idx = t; idx < 16 * 40 / 2; idx += NTHR) z1[idx] = 0;
        int* z2 = (int*)&h2g[0][0];
        for (int idx = t; idx < 16 * 40 / 2; idx += NTHR) z2[idx] = 0;
        int* z3 = (int*)&xhist[0][0];
        for (int idx = t; idx < 16 * 80 / 2; idx += NTHR) z3[idx] = 0;
    }
    if (t < 256) {
        int r = t >> 4, c0 = (t & 15) * 4;
        float4 v = *(const float4*)&uin[(long)(rowbase + r) * 64 + c0];
        uT[c0 + 0][r] = v.x; uT[c0 + 1][r] = v.y; uT[c0 + 2][r] = v.z; uT[c0 + 3][r] = v.w;
    }

    f32x4 acc2[8];
#pragma unroll
    for (int s = 0; s < 8; ++s) {
        float bb = b1p[(wv * 8 + s) * 16 + n];
        acc2[s] = (f32x4){bb, bb, bb, bb};
    }
    f32x4 zacc;
    {
        int pc = wv * 16 + n;
        float bz = b2[(pc >> 1) + 64 * (pc & 1)];
        zacc = (f32x4){bz, bz, bz, bz};
    }

    bf16x8 w1fE[8], w1fO[8], w2fE, w2fO, w0f[4];
#pragma unroll
    for (int s = 0; s < 8; ++s) {
        w1fO[s] = *(const bf16x8*)&W1f[(((long)0 * 64 + (wv * 8 + s)) * 64 + lane) * 8];
        w1fE[s] = *(const bf16x8*)&W1f[(((long)1 * 64 + (wv * 8 + s)) * 64 + lane) * 8];
    }
    w2fO = *(const bf16x8*)&W2f[(((long)0 * 8 + wv) * 64 + lane) * 8];
    w2fE = *(const bf16x8*)&W2f[(((long)1 * 8 + wv) * 64 + lane) * 8];
    if (wv == 7) {
#pragma unroll
        for (int f = 0; f < 4; ++f)
            w0f[f] = *(const bf16x8*)&W0f[(((long)0 * 4 + f) * 64 + lane) * 8];
    }

    f32x4 ldjacc = {0.f, 0.f, 0.f, 0.f};
    float ureg[4];

    BAR();
    if (t < 16) xhist[t][0] = (short)0x3F80;
#pragma unroll
    for (int r = 0; r < 4; ++r)
        ureg[r] = uT[8 * wv + (n >> 1)][aq * 4 + r];

    auto body = [&](int i, bf16x8* w1fS, bf16x8& w2fS) {
        const int g = i - 1;

        if (g >= 0 && wv == 7) {
            const int cgg = cntg(g);
            const bool two_k = (g >= 31);
            const bf16x8 ax0 = *(const bf16x8*)&xhist[n][aq * 8];
            f32x4 d0 = {0.f, 0.f, 0.f, 0.f};
            d0 = __builtin_amdgcn_mfma_f32_16x16x32_bf16(ax0, w0f[0], d0, 0, 0, 0);
            f32x4 d1 = {0.f, 0.f, 0.f, 0.f};
            if (two_k) {
                const bf16x8 ax1 = *(const bf16x8*)&xhist[n][32 + aq * 8];
                d0 = __builtin_amdgcn_mfma_f32_16x16x32_bf16(ax1, w0f[1], d0, 0, 0, 0);
                if (cgg == 17) {
                    d1 = __builtin_amdgcn_mfma_f32_16x16x32_bf16(ax0, w0f[2], d1, 0, 0, 0);
                    d1 = __builtin_amdgcn_mfma_f32_16x16x32_bf16(ax1, w0f[3], d1, 0, 0, 0);
                }
            } else if (cgg == 17) {
                d1 = __builtin_amdgcn_mfma_f32_16x16x32_bf16(ax0, w0f[2], d1, 0, 0, 0);
            }
            {
                const int gW = (i < 63) ? i : 62;
#pragma unroll
                for (int f = 0; f < 4; ++f)
                    w0f[f] = *(const bf16x8*)&W0f[(((long)gW * 4 + f) * 64 + lane) * 8];
            }
#pragma unroll
            for (int r = 0; r < 4; ++r) {
                float v = d0[r];
                h1g[aq * 4 + r][n] = f2bf(v > 0.f ? v : 0.f);
            }
            if (n == 0) {
#pragma unroll
                for (int r = 0; r < 4; ++r) {
                    float v = (cgg == 17) ? (d1[r] > 0.f ? d1[r] : 0.f) : 0.f;
                    h1g[aq * 4 + r][16] = f2bf(v);
                }
            }
        }
        BAR();

        if (g >= 0) {
            const int og = off1(g), cg = cntg(g);
            const int tf0 = og >> 4, tfl = (og + cg - 1) >> 4;
            const bf16x8 af = *(const bf16x8*)&h1g[n][aq * 8];
            const int s0 = tf0 - wv * 8;
#pragma unroll
            for (int s = 0; s < 8; ++s) {
                if (s >= s0)
                    acc2[s] = __builtin_amdgcn_mfma_f32_16x16x32_bf16(af, w1fS[s], acc2[s], 0, 0, 0);
            }
            if (i >= 1) {
                const int gp = (i + 1 < 63) ? (i + 1) : 62;
                const int s0p = (off1(gp) >> 4) - wv * 8;
#pragma unroll
                for (int s = 0; s < 8; ++s) {
                    if (s >= s0p)
                        w1fS[s] = *(const bf16x8*)&W1f[(((long)gp * 64 + (wv * 8 + s)) * 64 + lane) * 8];
                }
            }
            if (wv == (tf0 >> 3)) {
                const int s = tf0 & 7;
                const int j = tf0 * 16 + n - og;
                if (j >= 0 && j < cg) {
#pragma unroll
                    for (int r = 0; r < 4; ++r) {
                        float v = acc2[s][r];
                        h2g[aq * 4 + r][j] = f2bf(v > 0.f ? v : 0.f);
                    }
                }
            }
            if (tfl != tf0 && wv == (tfl >> 3)) {
                const int s = tfl & 7;
                const int j = tfl * 16 + n - og;
                if (j < cg) {
#pragma unroll
                    for (int r = 0; r < 4; ++r) {
                        float v = acc2[s][r];
                        h2g[aq * 4 + r][j] = f2bf(v > 0.f ? v : 0.f);
                    }
                }
            }
            if (g == 16 && wv == 0 && n == 0) {
#pragma unroll
                for (int r = 0; r < 4; ++r) h2g[aq * 4 + r][16] = 0;
            }
        }
        BAR();

        if (g >= 0) {
            const bf16x8 af3 = *(const bf16x8*)&h2g[n][aq * 8];
            zacc = __builtin_amdgcn_mfma_f32_16x16x32_bf16(af3, w2fS, zacc, 0, 0, 0);
            if (i >= 1) {
                const int gp = (i + 1 < 63) ? (i + 1) : 62;
                w2fS = *(const bf16x8*)&W2f[(((long)gp * 8 + wv) * 64 + lane) * 8];
            }
        }
        if (wv == (i >> 3)) {
            const int n0 = 2 * (i & 7);
            f32x4 sgv;
#pragma unroll
            for (int r = 0; r < 4; ++r) sgv[r] = __shfl_xor(zacc[r], 1);
            if (n == n0) {
#pragma unroll
                for (int r = 0; r < 4; ++r) {
                    const float sg = sgv[r], mu = zacc[r];
                    const float x = ureg[r] * __expf(sg) + mu;
                    ldjacc[r] += sg;
                    const int m = aq * 4 + r;
                    xLs[m][i] = x;
                    if (i < 63) xhist[m][i + 1] = f2bf(x);
                }
            }
        }
        BAR();
    };

#pragma unroll 1
    for (int i = 0; i < 64; i += 2) {
        body(i, w1fE, w2fE);
        body(i + 1, w1fO, w2fO);
    }

#pragma unroll
    for (int r = 0; r < 4; ++r) {
        float v = ldjacc[r];
        v += __shfl_xor(v, 2);
        v += __shfl_xor(v, 4);
        v += __shfl_xor(v, 8);
        if (n == 0) ldjpart[wv][aq * 4 + r] = v;
    }
    BAR();

    if (t < 256) {
        int r = t >> 4, c = (t & 15) * 4;
        float4 v;
        v.x = xLs[r][c]; v.y = xLs[r][c + 1]; v.z = xLs[r][c + 2]; v.w = xLs[r][c + 3];
        *(float4*)&out[(long)(rowbase + r) * 64 + c] = v;
    }
    if (t < 16) {
        float s = 0.f;
#pragma unroll
        for (int w = 0; w < 8; ++w) s += ldjpart[w][t];
        out[(long)BATCH * 64 + rowbase + t] = s;
    }
}

extern "C" void kernel_launch(void* const* d_in, const int* in_sizes, int n_in,
                              void* d_out, int out_size, void* d_ws, size_t ws_size,
                              hipStream_t stream) {
    (void)in_sizes; (void)n_in; (void)out_size; (void)ws_size;
    const float* u  = (const float*)d_in[0];
    const float* W0 = (const float*)d_in[1];
    const float* b0 = (const float*)d_in[2];
    const float* W1 = (const float*)d_in[3];
    const float* b1 = (const float*)d_in[4];
    const float* W2 = (const float*)d_in[5];
    const float* b2 = (const float*)d_in[6];
    float* out = (float*)d_out;

    short* W1f = (short*)d_ws;
    short* W2f = (short*)((char*)d_ws + 4128768);
    short* W0f = (short*)((char*)d_ws + 4128768 + 516096);
    float* b1p = (float*)((char*)d_ws + 4128768 + 516096 + 258048);

    prep5<<<dim3(89), dim3(256), 0, stream>>>(W0, b0, W1, b1, W2, W1f, W2f, W0f, b1p);
    made5<<<dim3(BATCH / 16), dim3(NTHR), 0, stream>>>(u, b2, W1f, W2f, W0f, b1p, out);
}

// Round 6
// 176.443 us; speedup vs baseline: 1.5947x; 1.1876x over previous
//
#include <hip/hip_runtime.h>
#include <hip/hip_bf16.h>

#define BATCH 4096
#define NTHR 512

typedef __attribute__((ext_vector_type(8))) short bf16x8;
typedef __attribute__((ext_vector_type(4))) float f32x4;
typedef __attribute__((ext_vector_type(4))) short short4v;

// CK-style barrier: drain LDS only, leave global prefetches in flight
#define BAR() asm volatile("s_waitcnt lgkmcnt(0)\n\ts_barrier" ::: "memory")

// dh-sorted packing: group g (= degree) has cnt(g) units, prefix off1(g)
__host__ __device__ __forceinline__ int off1(int g) { return (g <= 16) ? 17 * g : 16 * g + 16; }
__host__ __device__ __forceinline__ int cntg(int g) { return (g < 16) ? 17 : 16; }
__host__ __device__ __forceinline__ int unitOf(int p) {
    int gp, jp;
    if (p < 272) { gp = p / 17; jp = p - gp * 17; }
    else         { gp = (p >> 4) - 1; jp = p & 15; }
    return gp + 63 * jp;
}
__device__ __forceinline__ short f2bf(float f) {
    __hip_bfloat16 h = __float2bfloat16(f);
    return *reinterpret_cast<short*>(&h);
}

// ---------------- prep6: LDS-staged coalesced packing (512 thr) ----------------
// W1f [g][tile(64)][lane][8] : B[k][n] = W1[unit(tile*16+n)][g+63k], k<cnt(g)
// W2f [g][c(8)][lane][8]     : packed z col pc=c*16+n -> orig r=(pc>>1)+64*(pc&1)
// W0f [g][f(4)][lane][8]     : f=n2*2+kt; slot p=off1(g)+n2*16+(lane&15);
//     kp=kt*32+(lane>>4)*8+e; kp==0 -> b0[unit(p)]; kp-1<=g -> W0[unit(p)][kp-1]; else 0
// b1p [1024] f32 packed b1
__global__ void prep6(const float* __restrict__ W0, const float* __restrict__ b0,
                      const float* __restrict__ W1, const float* __restrict__ b1,
                      const float* __restrict__ W2,
                      short* __restrict__ W1f, short* __restrict__ W2f,
                      short* __restrict__ W0f, float* __restrict__ b1p) {
    __shared__ short ws[16][1024];
    const int b = blockIdx.x, t = threadIdx.x;
    if (b < 72) {
        const bool isW1 = (b < 64);
        const int n = t >> 5;                 // staged slot 0..15
        int u;
        if (isW1) u = unitOf(b * 16 + n);
        else { const int c = b - 64; u = (n & 1) ? (64 + c * 8 + (n >> 1)) : (c * 8 + (n >> 1)); }
        const float* src = isW1 ? (W1 + (long)u * 1024) : (W2 + (long)u * 1024);
        const int c0 = (t & 31) * 4;
#pragma unroll
        for (int j = 0; j < 8; ++j) {
            int c = c0 + j * 128;
            float4 v = *(const float4*)&src[c];
            short4v sv;
            sv[0] = f2bf(v.x); sv[1] = f2bf(v.y); sv[2] = f2bf(v.z); sv[3] = f2bf(v.w);
            *(short4v*)&ws[n][c] = sv;
        }
        __syncthreads();
#pragma unroll 1
        for (int it = 0; it < 8; ++it) {
            int v = t + it * 512;
            if (v < 4032) {
                int g = v >> 6, lane2 = v & 63;
                int nn = lane2 & 15, aq2 = lane2 >> 4;
                bf16x8 pk;
#pragma unroll
                for (int e = 0; e < 8; ++e) {
                    int k = aq2 * 8 + e;
                    pk[e] = (k < cntg(g)) ? ws[nn][g + 63 * k] : (short)0;
                }
                if (isW1) *(bf16x8*)&W1f[(((long)g * 64 + b) * 64 + lane2) * 8] = pk;
                else      *(bf16x8*)&W2f[(((long)g * 8 + (b - 64)) * 64 + lane2) * 8] = pk;
            }
        }
    } else if (b < 88) {
        const int bb = b - 72;
#pragma unroll 1
        for (int j = 0; j < 16; ++j) {
            int q = t + j * 512;
            if (q < 8064) {
                int idx = bb * 8064 + q;
                int g = idx >> 11, rem = idx & 2047;
                int n2 = rem >> 10, kt = (rem >> 9) & 1, lane2 = (rem >> 3) & 63, e = rem & 7;
                int sl = n2 * 16 + (lane2 & 15);
                int kp = kt * 32 + ((lane2 >> 4) << 3) + e;
                float val = 0.f;
                if (sl < cntg(g)) {
                    int u = unitOf(off1(g) + sl);
                    if (kp == 0) val = b0[u];
                    else if (kp - 1 <= g) val = W0[u * 64 + kp - 1];
                }
                W0f[idx] = f2bf(val);
            }
        }
    } else {
        for (int p = t; p < 1024; p += 512) b1p[p] = b1[unitOf(p)];
    }
}

// ---------------- made6: 2-window step; publisher does x + h1 in one window ----------------
__global__ __launch_bounds__(NTHR, 2) void made6(
    const float* __restrict__ uin, const float* __restrict__ b2,
    const short* __restrict__ W1f, const short* __restrict__ W2f,
    const short* __restrict__ W0f, const float* __restrict__ b1p,
    float* __restrict__ out) {

    __shared__ __align__(16) short h1g[16][40];   // group-g h1, [m][j], K-pad zeroed
    __shared__ __align__(16) short h2g[16][40];   // group-g h2, [m][j]
    __shared__ __align__(16) short xhist[16][80]; // [m][k']: k'=0 -> 1.0 (bias), k'=i+1 -> x_i
    __shared__ __align__(16) float uT[64][16];    // uT[i][m]
    __shared__ __align__(16) float xLs[16][68];   // staged x for final store
    __shared__ float ldjpart[8][16];

    const int t = threadIdx.x, lane = t & 63, wv = t >> 6;
    const int n = lane & 15, aq = lane >> 4;
    const int rowbase = blockIdx.x * 16;

    {   // zero h1g/h2g/xhist (K pads must stay 0)
        int* z1 = (int*)&h1g[0][0];
        for (int idx = t; idx < 16 * 40 / 2; idx += NTHR) z1[idx] = 0;
        int* z2 = (int*)&h2g[0][0];
        for (int idx = t; idx < 16 * 40 / 2; idx += NTHR) z2[idx] = 0;
        int* z3 = (int*)&xhist[0][0];
        for (int idx = t; idx < 16 * 80 / 2; idx += NTHR) z3[idx] = 0;
    }
    if (t < 256) {
        int r = t >> 4, c0 = (t & 15) * 4;
        float4 v = *(const float4*)&uin[(long)(rowbase + r) * 64 + c0];
        uT[c0 + 0][r] = v.x; uT[c0 + 1][r] = v.y; uT[c0 + 2][r] = v.z; uT[c0 + 3][r] = v.w;
    }

    // acc2: strided tile ownership (wave wv owns tiles wv+8s), b1 folded in
    f32x4 acc2[8];
#pragma unroll
    for (int s = 0; s < 8; ++s) {
        float bb = b1p[(wv + 8 * s) * 16 + n];
        acc2[s] = (f32x4){bb, bb, bb, bb};
    }
    // zacc: packed z col pc = wv*16+n (orig r = (pc>>1)+64*(pc&1)), b2 folded in
    f32x4 zacc;
    {
        int pc = wv * 16 + n;
        float bz = b2[(pc >> 1) + 64 * (pc & 1)];
        zacc = (f32x4){bz, bz, bz, bz};
    }

    // prefetch: W1f/W2f distance-2 (E/O sets); W0f per-publisher-wave distance-1
    bf16x8 w1fE[8], w1fO[8], w2fE, w2fO, w0f0, w0f1, w0f2;
#pragma unroll
    for (int s = 0; s < 8; ++s) {
        const int tile = wv + 8 * s;
        w1fO[s] = *(const bf16x8*)&W1f[(((long)0 * 64 + tile) * 64 + lane) * 8];
        w1fE[s] = *(const bf16x8*)&W1f[(((long)1 * 64 + tile) * 64 + lane) * 8];
    }
    w2fO = *(const bf16x8*)&W2f[(((long)0 * 8 + wv) * 64 + lane) * 8];
    w2fE = *(const bf16x8*)&W2f[(((long)1 * 8 + wv) * 64 + lane) * 8];
    {
        const long gb = 8 * wv;   // first group this wave will publish (<= 56)
        w0f0 = *(const bf16x8*)&W0f[((gb * 4 + 0) * 64 + lane) * 8];
        w0f1 = *(const bf16x8*)&W0f[((gb * 4 + 1) * 64 + lane) * 8];
        w0f2 = *(const bf16x8*)&W0f[((gb * 4 + 2) * 64 + lane) * 8];
    }

    f32x4 ldjacc = {0.f, 0.f, 0.f, 0.f};
    BAR();
    if (t < 16) xhist[t][0] = (short)0x3F80;   // bias column = 1.0 (wave 0; same-wave use in Q(0))
    float ureg[4];
#pragma unroll
    for (int r = 0; r < 4; ++r) ureg[r] = uT[8 * wv + (n >> 1)][aq * 4 + r];

    auto body = [&](int i, bf16x8* w1fS, bf16x8& w2fS) {
        const int g = i - 1;
        // ===== P: bulk acc2 += h1[g]*W1 (live tiles), owners finalize h2[g] =====
        if (g >= 0) {
            const int og = off1(g), cg = cntg(g);
            const int tf0 = og >> 4, tfl = (og + cg - 1) >> 4;
            const int s0 = (tf0 > wv) ? ((tf0 - wv + 7) >> 3) : 0;
            if (s0 < 8) {
                const bf16x8 af = *(const bf16x8*)&h1g[n][aq * 8];
#pragma unroll
                for (int s = 0; s < 8; ++s)
                    if (s >= s0)
                        acc2[s] = __builtin_amdgcn_mfma_f32_16x16x32_bf16(af, w1fS[s], acc2[s], 0, 0, 0);
            }
            {   // prefetch W1f group i+1 into this parity set (consumed P(i+2))
                const int gp = (i + 1 < 63) ? (i + 1) : 62;
                const int tf0p = off1(gp) >> 4;
                const int s0p = (tf0p > wv) ? ((tf0p - wv + 7) >> 3) : 0;
#pragma unroll
                for (int s = 0; s < 8; ++s)
                    if (s >= s0p)
                        w1fS[s] = *(const bf16x8*)&W1f[(((long)gp * 64 + (wv + 8 * s)) * 64 + lane) * 8];
            }
            if (wv == (tf0 & 7)) {            // owner-direct finalize (strided map: s = T>>3)
                const int sT = tf0 >> 3;
                const int j = tf0 * 16 + n - og;
                if (j >= 0 && j < cg) {
#pragma unroll
                    for (int r = 0; r < 4; ++r) {
                        float v = acc2[sT][r];
                        h2g[aq * 4 + r][j] = f2bf(v > 0.f ? v : 0.f);
                    }
                }
            }
            if (tfl != tf0 && wv == (tfl & 7)) {
                const int sT = tfl >> 3;
                const int j = tfl * 16 + n - og;
                if (j < cg) {
#pragma unroll
                    for (int r = 0; r < 4; ++r) {
                        float v = acc2[sT][r];
                        h2g[aq * 4 + r][j] = f2bf(v > 0.f ? v : 0.f);
                    }
                }
            }
            if (g == 16 && wv == 0 && n == 0) {   // first 16-wide group: clear stale col 16
#pragma unroll
                for (int r = 0; r < 4; ++r) h2g[aq * 4 + r][16] = 0;
            }
        }
        BAR();   // h2g visible
        // ===== Q: all waves zacc += h2[g]*W2; publisher: x_i then h1[group i] =====
        if (g >= 0) {
            const bf16x8 af3 = *(const bf16x8*)&h2g[n][aq * 8];
            zacc = __builtin_amdgcn_mfma_f32_16x16x32_bf16(af3, w2fS, zacc, 0, 0, 0);
            const int gp = (i + 1 < 63) ? (i + 1) : 62;
            w2fS = *(const bf16x8*)&W2f[(((long)gp * 8 + wv) * 64 + lane) * 8];
        }
        if (wv == (i >> 3)) {
            const int n0 = 2 * (i & 7);       // packed col 2i = mu, 2i+1 = sigma
            f32x4 sgv;
#pragma unroll
            for (int r = 0; r < 4; ++r) sgv[r] = __shfl_xor(zacc[r], 1);
            if (n == n0) {
#pragma unroll
                for (int r = 0; r < 4; ++r) {
                    const float sg = sgv[r], mu = zacc[r];
                    const float x = ureg[r] * __expf(sg) + mu;
                    ldjacc[r] += sg;
                    const int m = aq * 4 + r;
                    xLs[m][i] = x;
                    if (i < 63) xhist[m][i + 1] = f2bf(x);
                }
            }
            if (i < 63) {   // h1[group i] from xhist (same-wave writes; lgkmcnt only)
                const bf16x8 ax0 = *(const bf16x8*)&xhist[n][aq * 8];
                f32x4 d0 = {0.f, 0.f, 0.f, 0.f};
                d0 = __builtin_amdgcn_mfma_f32_16x16x32_bf16(ax0, w0f0, d0, 0, 0, 0);
                if (i >= 31) {                // K extent i+2 > 32: second k-tile
                    const bf16x8 ax1 = *(const bf16x8*)&xhist[n][32 + aq * 8];
                    d0 = __builtin_amdgcn_mfma_f32_16x16x32_bf16(ax1, w0f1, d0, 0, 0, 0);
                }
                f32x4 d1 = {0.f, 0.f, 0.f, 0.f};
                if (i < 16)                   // 17-wide groups: col-16 tile (extent <=17, 1 k-tile)
                    d1 = __builtin_amdgcn_mfma_f32_16x16x32_bf16(ax0, w0f2, d1, 0, 0, 0);
#pragma unroll
                for (int r = 0; r < 4; ++r) {
                    float v = d0[r];
                    h1g[aq * 4 + r][n] = f2bf(v > 0.f ? v : 0.f);
                }
                if (n == 0) {
#pragma unroll
                    for (int r = 0; r < 4; ++r) {
                        float v = (i < 16) ? (d1[r] > 0.f ? d1[r] : 0.f) : 0.f;
                        h1g[aq * 4 + r][16] = f2bf(v);
                    }
                }
                if (i + 1 < 63 && ((i + 1) >> 3) == wv) {   // next group still ours: prefetch
                    const long gb = i + 1;
                    w0f0 = *(const bf16x8*)&W0f[((gb * 4 + 0) * 64 + lane) * 8];
                    w0f1 = *(const bf16x8*)&W0f[((gb * 4 + 1) * 64 + lane) * 8];
                    w0f2 = *(const bf16x8*)&W0f[((gb * 4 + 2) * 64 + lane) * 8];
                }
            }
        }
        BAR();   // h1g / xhist / xLs visible
    };

#pragma unroll 1
    for (int i = 0; i < 64; i += 2) {
        body(i, w1fE, w2fE);
        body(i + 1, w1fO, w2fO);
    }

    // ldj: publisher lanes are even n; xor-reduce over even lanes, then across waves
#pragma unroll
    for (int r = 0; r < 4; ++r) {
        float v = ldjacc[r];
        v += __shfl_xor(v, 2);
        v += __shfl_xor(v, 4);
        v += __shfl_xor(v, 8);
        if (n == 0) ldjpart[wv][aq * 4 + r] = v;
    }
    BAR();

    if (t < 256) {
        int r = t >> 4, c = (t & 15) * 4;
        float4 v;
        v.x = xLs[r][c]; v.y = xLs[r][c + 1]; v.z = xLs[r][c + 2]; v.w = xLs[r][c + 3];
        *(float4*)&out[(long)(rowbase + r) * 64 + c] = v;
    }
    if (t < 16) {
        float s = 0.f;
#pragma unroll
        for (int w = 0; w < 8; ++w) s += ldjpart[w][t];
        out[(long)BATCH * 64 + rowbase + t] = s;
    }
}

extern "C" void kernel_launch(void* const* d_in, const int* in_sizes, int n_in,
                              void* d_out, int out_size, void* d_ws, size_t ws_size,
                              hipStream_t stream) {
    (void)in_sizes; (void)n_in; (void)out_size; (void)ws_size;
    const float* u  = (const float*)d_in[0];
    const float* W0 = (const float*)d_in[1];
    const float* b0 = (const float*)d_in[2];
    const float* W1 = (const float*)d_in[3];
    const float* b1 = (const float*)d_in[4];
    const float* W2 = (const float*)d_in[5];
    const float* b2 = (const float*)d_in[6];
    float* out = (float*)d_out;

    // d_ws layout (bytes): W1f 4,128,768 | W2f 516,096 | W0f 258,048 | b1p 4,096
    short* W1f = (short*)d_ws;
    short* W2f = (short*)((char*)d_ws + 4128768);
    short* W0f = (short*)((char*)d_ws + 4128768 + 516096);
    float* b1p = (float*)((char*)d_ws + 4128768 + 516096 + 258048);

    prep6<<<dim3(89), dim3(512), 0, stream>>>(W0, b0, W1, b1, W2, W1f, W2f, W0f, b1p);
    made6<<<dim3(BATCH / 16), dim3(NTHR), 0, stream>>>(u, b2, W1f, W2f, W0f, b1p, out);
}